// Round 1
// baseline (83.598 us; speedup 1.0000x reference)
//
#include <hip/hip_runtime.h>

// GroupNorm+Swish backward, fused single kernel.
// N=32, C=64, G=32, CG=2, HXW=16384.
// dy:(N,G,CG,HXW)  mean:(N,G)  rstd:(N,G)  x:(N,C,H,W)  gamma:(C)  beta:(C)
// out = [dx (N*C*HXW) | dgamma (C*HXW) | dbeta (C*HXW)]
// dy, x, dx all share flat layout [N][C][HXW].

#define N_TOT 32
#define C_TOT 64
#define G_TOT 32
#define HXW_TOT 16384
#define HXW4 (HXW_TOT / 4)

__global__ __launch_bounds__(256) void gnswish_bwd(
    const float* __restrict__ dy,
    const float* __restrict__ mean,
    const float* __restrict__ rstd,
    const float* __restrict__ x,
    const float* __restrict__ gamma,
    const float* __restrict__ beta,
    float* __restrict__ out)
{
    const int hw4 = blockIdx.x * blockDim.x + threadIdx.x;  // 0..4095 (float4 idx)
    const int c   = blockIdx.y;                             // 0..63
    const int g   = c >> 1;                                 // CG = 2

    const float gam = gamma[c];
    const float bet = beta[c];

    const float4* __restrict__ dy4 = (const float4*)dy;
    const float4* __restrict__ x4  = (const float4*)x;
    float4* __restrict__ dx4       = (float4*)out;

    float dg0 = 0.f, dg1 = 0.f, dg2 = 0.f, dg3 = 0.f;
    float db0 = 0.f, db1 = 0.f, db2 = 0.f, db3 = 0.f;

#pragma unroll 2
    for (int n = 0; n < N_TOT; ++n) {
        const float mu = mean[n * G_TOT + g];   // block-uniform -> s_load
        const float rs = rstd[n * G_TOT + g];
        const long  idx = (long)(n * C_TOT + c) * HXW4 + hw4;

        const float4 d  = dy4[idx];
        const float4 xv = x4[idx];

        float4 dxv;

        // component macro: xn, out, fast sigmoid, swish grad
#define DO_COMP(XX, DD, DGG, DBB, DXX)                                   \
        {                                                                \
            float xn  = (XX - mu) * rs;                                  \
            float o   = xn * gam + bet;                                  \
            float sig = __builtin_amdgcn_rcpf(1.0f + __expf(-o));        \
            float sw  = o * sig;                                         \
            float sg  = sig + sw * (1.0f - sig);                         \
            float ds  = DD * sg;                                         \
            DGG += ds * xn;                                              \
            DBB += ds;                                                   \
            DXX = ds * gam * rs;                                         \
        }

        DO_COMP(xv.x, d.x, dg0, db0, dxv.x)
        DO_COMP(xv.y, d.y, dg1, db1, dxv.y)
        DO_COMP(xv.z, d.z, dg2, db2, dxv.z)
        DO_COMP(xv.w, d.w, dg3, db3, dxv.w)
#undef DO_COMP

        dx4[idx] = dxv;
    }

    // dgamma at float offset N*C*HXW, dbeta at N*C*HXW + C*HXW
    const long dg_base = (long)N_TOT * C_TOT * HXW4;      // in float4 units
    const long db_base = dg_base + (long)C_TOT * HXW4;
    const long col     = (long)c * HXW4 + hw4;

    float4* __restrict__ o4 = (float4*)out;
    o4[dg_base + col] = make_float4(dg0, dg1, dg2, dg3);
    o4[db_base + col] = make_float4(db0, db1, db2, db3);
}

extern "C" void kernel_launch(void* const* d_in, const int* in_sizes, int n_in,
                              void* d_out, int out_size, void* d_ws, size_t ws_size,
                              hipStream_t stream) {
    const float* dy    = (const float*)d_in[0];
    const float* mean  = (const float*)d_in[1];
    const float* rstd  = (const float*)d_in[2];
    const float* x     = (const float*)d_in[3];
    const float* gamma = (const float*)d_in[4];
    const float* beta  = (const float*)d_in[5];
    float* out = (float*)d_out;

    dim3 grid(HXW4 / 256, C_TOT);  // 16 x 64 = 1024 blocks
    dim3 block(256);
    gnswish_bwd<<<grid, block, 0, stream>>>(dy, mean, rstd, x, gamma, beta, out);
}

// Round 2
// 67.038 us; speedup vs baseline: 1.2470x; 1.2470x over previous
//
#include <hip/hip_runtime.h>

// GroupNorm+Swish backward, fused single kernel. Round 2: latency-bound fix.
// N=32, C=64, G=32, CG=2, HXW=16384.
// dy:(N,G,CG,HXW)  mean:(N,G)  rstd:(N,G)  x:(N,C,H,W)  gamma:(C)  beta:(C)
// out = [dx (N*C*HXW) | dgamma (C*HXW) | dbeta (C*HXW)]
// dy, x, dx all share flat layout [N][C][HXW].
//
// R1 post-mortem: 1024 blocks -> 16 waves/CU (36% occ), 2.4 TB/s, VALUBusy 9%
// => latency-bound. Fix: float2 granularity -> 2048 blocks (32 waves/CU),
// unroll 4 (8 loads in flight/wave), nontemporal output stores (outputs never
// re-read; preserve dy/x L3 residency which currently halves FETCH_SIZE).

#define N_TOT 32
#define C_TOT 64
#define G_TOT 32
#define HXW_TOT 16384
#define HXW2 (HXW_TOT / 2)

typedef float f2 __attribute__((ext_vector_type(2)));

__global__ __launch_bounds__(256) void gnswish_bwd(
    const float* __restrict__ dy,
    const float* __restrict__ mean,
    const float* __restrict__ rstd,
    const float* __restrict__ x,
    const float* __restrict__ gamma,
    const float* __restrict__ beta,
    float* __restrict__ out)
{
    const int hw2 = blockIdx.x * blockDim.x + threadIdx.x;  // 0..8191 (float2 idx)
    const int c   = blockIdx.y;                             // 0..63
    const int g   = c >> 1;                                 // CG = 2

    const float gam = gamma[c];
    const float bet = beta[c];

    const f2* __restrict__ dy2 = (const f2*)dy;
    const f2* __restrict__ x2  = (const f2*)x;
    f2* __restrict__ dx2       = (f2*)out;

    float dg0 = 0.f, dg1 = 0.f;
    float db0 = 0.f, db1 = 0.f;

#pragma unroll 4
    for (int n = 0; n < N_TOT; ++n) {
        const float mu = mean[n * G_TOT + g];   // block-uniform -> s_load
        const float rs = rstd[n * G_TOT + g];
        const long  idx = (long)(n * C_TOT + c) * HXW2 + hw2;

        const f2 d  = dy2[idx];
        const f2 xv = x2[idx];

        f2 dxv;

#define DO_COMP(XX, DD, DGG, DBB, DXX)                                   \
        {                                                                \
            float xn  = (XX - mu) * rs;                                  \
            float o   = xn * gam + bet;                                  \
            float sig = __builtin_amdgcn_rcpf(1.0f + __expf(-o));        \
            float sw  = o * sig;                                         \
            float sg  = sig + sw * (1.0f - sig);                         \
            float ds  = DD * sg;                                         \
            DGG += ds * xn;                                              \
            DBB += ds;                                                   \
            DXX = ds * (gam * rs);                                       \
        }

        DO_COMP(xv.x, d.x, dg0, db0, dxv.x)
        DO_COMP(xv.y, d.y, dg1, db1, dxv.y)
#undef DO_COMP

        __builtin_nontemporal_store(dxv, &dx2[idx]);
    }

    // dgamma at float offset N*C*HXW, dbeta at N*C*HXW + C*HXW (in f2 units)
    const long dg_base = (long)N_TOT * C_TOT * HXW2;
    const long db_base = dg_base + (long)C_TOT * HXW2;
    const long col     = (long)c * HXW2 + hw2;

    f2* __restrict__ o2 = (f2*)out;
    f2 dgv; dgv.x = dg0; dgv.y = dg1;
    f2 dbv; dbv.x = db0; dbv.y = db1;
    __builtin_nontemporal_store(dgv, &o2[dg_base + col]);
    __builtin_nontemporal_store(dbv, &o2[db_base + col]);
}

extern "C" void kernel_launch(void* const* d_in, const int* in_sizes, int n_in,
                              void* d_out, int out_size, void* d_ws, size_t ws_size,
                              hipStream_t stream) {
    const float* dy    = (const float*)d_in[0];
    const float* mean  = (const float*)d_in[1];
    const float* rstd  = (const float*)d_in[2];
    const float* x     = (const float*)d_in[3];
    const float* gamma = (const float*)d_in[4];
    const float* beta  = (const float*)d_in[5];
    float* out = (float*)d_out;

    dim3 grid(HXW2 / 256, C_TOT);  // 32 x 64 = 2048 blocks -> 8 wg/CU, 100% occ cap
    dim3 block(256);
    gnswish_bwd<<<grid, block, 0, stream>>>(dy, mean, rstd, x, gamma, beta, out);
}